// Round 1
// baseline (174.388 us; speedup 1.0000x reference)
//
#include <hip/hip_runtime.h>
#include <hip/hip_bf16.h>
#include <math.h>

// KoLeo loss: B=8, T=4096, D=256 fp32 input.
// Phase 1: convert x -> bf16 (ws)
// Phase 2: per-batch Gram X·X^T via bf16 MFMA, streaming per-row argmax (diag excluded)
// Phase 3: exact fp32 distances to argmax neighbor, loss = -mean(log(dist+eps))

#define Bq 8
#define Tq 4096
#define Dq 256

typedef __attribute__((ext_vector_type(8))) short bf16x8;
typedef __attribute__((ext_vector_type(4))) float f32x4;

__device__ __forceinline__ unsigned short f2bf(float f) {
    unsigned int u = __float_as_uint(f);
    unsigned int r = (u + 0x7fffu + ((u >> 16) & 1u)) >> 16;   // RNE
    return (unsigned short)r;
}

// ---------------- Phase 1: fp32 -> bf16 ----------------
__global__ void cvt_kernel(const float* __restrict__ x, unsigned short* __restrict__ xb) {
    int i = blockIdx.x * blockDim.x + threadIdx.x;  // one float4 per thread
    const int n4 = Bq * Tq * Dq / 4;
    if (i < n4) {
        float4 v = ((const float4*)x)[i];
        ushort4 o;
        o.x = f2bf(v.x); o.y = f2bf(v.y); o.z = f2bf(v.z); o.w = f2bf(v.w);
        ((ushort4*)xb)[i] = o;
    }
}

// ---------------- Phase 2: Gram + streaming argmax ----------------
// Grid: 256 blocks = 8 batches x 32 row-tiles (batch = bid & 7 for XCD/L2 affinity).
// Block: 512 threads = 8 waves (2 M-waves x 4 N-waves).
// Block tile: 128 rows x (all 4096 cols, in 32 tiles of 128).
// Wave tile per s-tile: 64 rows (4 x 16) x 32 cols (2 x 16), K = 256 = 8 x 32.
// mfma_f32_16x16x32_bf16:
//   A frag: lane holds A[lane&15][ (lane>>4)*8 + j ]  (8 contiguous k -> 16B load)
//   B frag: lane holds B[(lane>>4)*8 + j][ lane&15 ]  (same pattern on X row)
//   C/D:    col = lane&15, row = (lane>>4)*4 + reg    (verified layout)
__global__ __launch_bounds__(512, 2)
void argmax_kernel(const unsigned short* __restrict__ xb, int* __restrict__ nn_idx) {
    const int bid   = blockIdx.x;
    const int batch = bid & 7;
    const int rowTile = bid >> 3;          // 0..31
    const int tid  = threadIdx.x;
    const int lane = tid & 63;
    const int wave = tid >> 6;             // 0..7
    const int waveM = wave >> 2;           // 0..1
    const int waveN = wave & 3;            // 0..3
    const int lrow = lane & 15;            // A-row / B-col / C-col
    const int lk   = lane >> 4;            // k-group / C row-group

    const unsigned short* xB = xb + (size_t)batch * Tq * Dq;
    const int rowBase = rowTile * 128 + waveM * 64;

    // A fragments, register resident: afrag[kk][mi]
    bf16x8 afrag[8][4];
#pragma unroll
    for (int mi = 0; mi < 4; ++mi) {
        const unsigned short* rp = xB + (size_t)(rowBase + mi * 16 + lrow) * Dq + lk * 8;
#pragma unroll
        for (int kk = 0; kk < 8; ++kk)
            afrag[kk][mi] = *(const bf16x8*)(rp + kk * 32);
    }

    float best[4][4];   // [mi][j]
    int   bidx[4][4];
#pragma unroll
    for (int mi = 0; mi < 4; ++mi)
#pragma unroll
        for (int j = 0; j < 4; ++j) { best[mi][j] = -1e30f; bidx[mi][j] = 0; }

    for (int st = 0; st < 32; ++st) {
        const int sBase = st * 128 + waveN * 32;
        f32x4 acc[4][2];
#pragma unroll
        for (int mi = 0; mi < 4; ++mi)
#pragma unroll
            for (int ni = 0; ni < 2; ++ni)
                acc[mi][ni] = (f32x4){0.f, 0.f, 0.f, 0.f};

#pragma unroll
        for (int kk = 0; kk < 8; ++kk) {
            bf16x8 bfr[2];
#pragma unroll
            for (int ni = 0; ni < 2; ++ni) {
                const int s = sBase + ni * 16 + lrow;
                bfr[ni] = *(const bf16x8*)(xB + (size_t)s * Dq + kk * 32 + lk * 8);
            }
#pragma unroll
            for (int mi = 0; mi < 4; ++mi)
#pragma unroll
                for (int ni = 0; ni < 2; ++ni)
                    acc[mi][ni] = __builtin_amdgcn_mfma_f32_16x16x32_bf16(
                        afrag[kk][mi], bfr[ni], acc[mi][ni], 0, 0, 0);
        }

        // streaming argmax update (exclude diagonal s == t)
#pragma unroll
        for (int mi = 0; mi < 4; ++mi) {
            const int tbase = rowBase + mi * 16 + lk * 4;
#pragma unroll
            for (int j = 0; j < 4; ++j) {
                const int tj = tbase + j;
#pragma unroll
                for (int ni = 0; ni < 2; ++ni) {
                    const float v = acc[mi][ni][j];
                    const int s = sBase + ni * 16 + lrow;
                    const bool ok = (s != tj) && (v > best[mi][j]);
                    best[mi][j] = ok ? v : best[mi][j];
                    bidx[mi][j] = ok ? s : bidx[mi][j];
                }
            }
        }
    }

    // reduce across the 16 lanes (lane&15) that share each C-row
    __shared__ float s_val[128][4];
    __shared__ int   s_idx[128][4];
#pragma unroll
    for (int mi = 0; mi < 4; ++mi) {
#pragma unroll
        for (int j = 0; j < 4; ++j) {
            float v = best[mi][j];
            int   ix = bidx[mi][j];
#pragma unroll
            for (int m = 8; m >= 1; m >>= 1) {
                float ov = __shfl_xor(v, m, 64);
                int   oi = __shfl_xor(ix, m, 64);
                if (ov > v || (ov == v && oi < ix)) { v = ov; ix = oi; }
            }
            if (lrow == 0) {
                const int rl = waveM * 64 + mi * 16 + lk * 4 + j;
                s_val[rl][waveN] = v;
                s_idx[rl][waveN] = ix;
            }
        }
    }
    __syncthreads();

    // reduce across the 4 N-waves; one thread per row
    if (tid < 128) {
        float v = s_val[tid][0];
        int  ix = s_idx[tid][0];
#pragma unroll
        for (int c = 1; c < 4; ++c) {
            float ov = s_val[tid][c];
            int   oi = s_idx[tid][c];
            if (ov > v || (ov == v && oi < ix)) { v = ov; ix = oi; }
        }
        nn_idx[batch * Tq + rowTile * 128 + tid] = ix;
    }
}

// ---------------- Phase 3: exact fp32 distance + loss ----------------
__global__ void loss_kernel(const float* __restrict__ x, const int* __restrict__ nn,
                            float* __restrict__ out) {
    const int lane = threadIdx.x & 63;
    const int wave = threadIdx.x >> 6;          // 4 waves / block
    const int gw = blockIdx.x * 4 + wave;       // 1024 global waves
    float lsum = 0.f;

    for (int row = gw; row < Bq * Tq; row += 1024) {
        const int b = row >> 12;
        const int t = row & (Tq - 1);
        const int s = nn[row];
        const float4* xt = (const float4*)(x + ((size_t)b * Tq + t) * Dq);
        const float4* xs = (const float4*)(x + ((size_t)b * Tq + s) * Dq);
        float4 a = xt[lane];
        float4 c = xs[lane];
        float dx = a.x - c.x + 1e-8f;
        float dy = a.y - c.y + 1e-8f;
        float dz = a.z - c.z + 1e-8f;
        float dw = a.w - c.w + 1e-8f;
        float sum = dx * dx + dy * dy + dz * dz + dw * dw;
#pragma unroll
        for (int m = 32; m >= 1; m >>= 1)
            sum += __shfl_xor(sum, m, 64);
        if (lane == 0)
            lsum += logf(sqrtf(sum) + 1e-8f);
    }

    __shared__ float red[4];
    if (lane == 0) red[wave] = lsum;
    __syncthreads();
    if (threadIdx.x == 0) {
        float s = red[0] + red[1] + red[2] + red[3];
        atomicAdd(out, -s * (1.0f / (Bq * Tq)));
    }
}

extern "C" void kernel_launch(void* const* d_in, const int* in_sizes, int n_in,
                              void* d_out, int out_size, void* d_ws, size_t ws_size,
                              hipStream_t stream) {
    const float* x = (const float*)d_in[0];
    float* out = (float*)d_out;

    unsigned short* xb = (unsigned short*)d_ws;                       // 16 MB bf16 copy
    int* nn = (int*)((char*)d_ws + (size_t)Bq * Tq * Dq * 2);         // 128 KB indices

    hipMemsetAsync(d_out, 0, sizeof(float), stream);

    const int n4 = Bq * Tq * Dq / 4;
    cvt_kernel<<<n4 / 256, 256, 0, stream>>>(x, xb);
    argmax_kernel<<<256, 512, 0, stream>>>(xb, nn);
    loss_kernel<<<256, 256, 0, stream>>>(x, nn, out);
}